// Round 11
// baseline (251.694 us; speedup 1.0000x reference)
//
#include <hip/hip_runtime.h>
#include <hip/hip_bf16.h>

#define NELEM 16384
#define DIN 768
#define DMID 128
#define DOUT 4
#define NBW 100000   // global key bitmap words (keys < 100000*32)
#define CH 391       // bitmap words per scan-chunk (256*391 >= NBW)

typedef __attribute__((ext_vector_type(8))) short short8;
typedef __attribute__((ext_vector_type(4))) float f32x4;

__device__ __forceinline__ unsigned f2bf(float f) {
    unsigned u = __float_as_uint(f);
    return (u + 0x7FFFu + ((u >> 16) & 1u)) >> 16;   // RNE bf16
}
__device__ __forceinline__ unsigned aload(const unsigned* p) {
    return __hip_atomic_load((unsigned*)p, __ATOMIC_RELAXED, __HIP_MEMORY_SCOPE_AGENT);
}
__device__ __forceinline__ void aor(unsigned* p, unsigned v) {
    __hip_atomic_fetch_or(p, v, __ATOMIC_RELAXED, __HIP_MEMORY_SCOPE_AGENT);
}
// threshold barrier; counter zeroed by the launch-time memset (proven R9/R10)
__device__ __forceinline__ void gbar(unsigned* cnt, unsigned thresh) {
    __syncthreads();
    if (threadIdx.x == 0) {
        __hip_atomic_fetch_add(cnt, 1u, __ATOMIC_ACQ_REL, __HIP_MEMORY_SCOPE_AGENT);
        while (__hip_atomic_load(cnt, __ATOMIC_RELAXED, __HIP_MEMORY_SCOPE_AGENT) < thresh)
            __builtin_amdgcn_s_sleep(1);
        (void)__hip_atomic_load(cnt, __ATOMIC_ACQUIRE, __HIP_MEMORY_SCOPE_AGENT);
    }
    __syncthreads();
}
__device__ __forceinline__ unsigned wscan_inc(unsigned x, int lane) {
    unsigned inc = x;
#pragma unroll
    for (int off = 1; off < 64; off <<= 1) {
        unsigned y = __shfl_up(inc, off);
        if (lane >= off) inc += y;
    }
    return inc;
}

// ===========================================================================
// FAST3 ws layout:
//   Gb@0(64K) SD@65536(64K) WtG@131072(192K) bitmap@327680(400000) bar@727680
//   total 727744.  Memset zeroes [bitmap, bar+64) = 400064 B.
// Gb word = vocab<<9 | s (grouped per batch row, vocab-ascending)
// SD[u]   = b<<19 | start<<10 | len
// ===========================================================================
#define FAST3_WS 727744

// K1: 32 blocks (one per batch row) x 256 threads. ONE global barrier.
__global__ __launch_bounds__(256) void group2_kernel(
    const int* __restrict__ vocab_ids, const float* __restrict__ W1,
    unsigned* __restrict__ Gb, unsigned* __restrict__ SD,
    unsigned short* __restrict__ WtG, unsigned* __restrict__ bitmap,
    unsigned* __restrict__ bar, float* __restrict__ out_ids) {
    __shared__ unsigned lbm[4096];       // 16 KB row vocab bitmap (2^17 bits)
    __shared__ unsigned voc[512];
    __shared__ unsigned short gel[512];  // group idx per element (+leader flag)
    __shared__ unsigned gcnt[512];
    __shared__ unsigned gstart[512];
    __shared__ unsigned part[256];
    __shared__ unsigned gbase[256];
    __shared__ unsigned wsumL[4];
    __shared__ unsigned Ush;

    const int t = threadIdx.x;
    const int b = blockIdx.x;
    const int lane = t & 63;
    const int wv = t >> 6;

    // ---- W1^T -> bf16 (coalesced reads; 3072 elems per block) ----
#pragma unroll
    for (int i = 0; i < 12; ++i) {
        int j = b * 3072 + i * 256 + t;   // 0..98303
        int k = j >> 7, c = j & 127;
        WtG[c * DIN + k] = (unsigned short)f2bf(W1[j]);
    }

    // ---- load row, mark GLOBAL bitmap, zero LDS ----
#pragma unroll
    for (int i = 0; i < 16; ++i) lbm[t + 256 * i] = 0;
    gcnt[t] = 0; gcnt[t + 256] = 0;
#pragma unroll
    for (int q = 0; q < 2; ++q) {
        int s = q * 256 + t;
        unsigned v = (unsigned)vocab_ids[b * 512 + s];
        voc[s] = v;
        unsigned key = v * 32u + (unsigned)b;
        aor(&bitmap[key >> 5], 1u << (key & 31u));   // idempotent
    }
    __syncthreads();
    // ---- local bitmap mark ----
#pragma unroll
    for (int q = 0; q < 2; ++q) {
        unsigned v = voc[q * 256 + t];
        atomicOr(&lbm[v >> 5], 1u << (v & 31u));
    }
    __syncthreads();
    // ---- local chunk-scan (16 words/thread) -> part[] = exclusive base ----
    {
        unsigned sum = 0;
#pragma unroll
        for (int j = 0; j < 16; ++j) sum += (unsigned)__popc(lbm[t * 16 + j]);
        unsigned inc = wscan_inc(sum, lane);
        if (lane == 63) wsumL[wv] = inc;
        __syncthreads();
        unsigned woff = 0;
        for (int i = 0; i < wv; ++i) woff += wsumL[i];
        part[t] = woff + inc - sum;
        __syncthreads();
    }
    // ---- per-element group index g; count group sizes ----
#pragma unroll
    for (int q = 0; q < 2; ++q) {
        int s = q * 256 + t;
        unsigned v = voc[s];
        unsigned lw = v >> 5, c = lw >> 4;
        unsigned g = part[c];
        for (unsigned j = c * 16; j < lw; ++j) g += (unsigned)__popc(lbm[j]);
        g += (unsigned)__popc(lbm[lw] & ((1u << (v & 31u)) - 1u));
        gel[s] = (unsigned short)g;
        atomicAdd(&gcnt[g], 1u);                      // counts only: deterministic
    }
    __syncthreads();
    // ---- exclusive scan gcnt[512] -> gstart ----
    {
        unsigned a = gcnt[2 * t], b2 = gcnt[2 * t + 1];
        unsigned pair = a + b2;
        unsigned inc = wscan_inc(pair, lane);
        if (lane == 63) wsumL[wv] = inc;
        __syncthreads();
        unsigned woff = 0;
        for (int i = 0; i < wv; ++i) woff += wsumL[i];
        unsigned excl = woff + inc - pair;
        gstart[2 * t] = excl;
        gstart[2 * t + 1] = excl + a;
    }
    __syncthreads();
    // ---- deterministic member index + grouped Gb write + leader flag ----
#pragma unroll
    for (int q = 0; q < 2; ++q) {
        int s = q * 256 + t;
        unsigned g = gel[s];
        unsigned m = 0;
        if (gcnt[g] > 1) {                            // rare (~1.3/row)
            unsigned v = voc[s];
            for (int j = 0; j < s; ++j) if (voc[j] == v) ++m;
        }
        Gb[b * 512 + gstart[g] + m] = (voc[s] << 9) | (unsigned)s;
        if (m == 0) gel[s] = (unsigned short)(g | 0x8000u);
    }

    gbar(bar, 32);   // THE one global barrier: global bitmap complete

    // ---- redundant global chunk-scan (CH words/thread) -> gbase[], U ----
    {
        unsigned sum = 0;
        int w0 = t * CH;
        for (int j = 0; j < CH; ++j) {
            int w = w0 + j;
            if (w < NBW) sum += (unsigned)__popc(aload(&bitmap[w]));
        }
        unsigned inc = wscan_inc(sum, lane);
        if (lane == 63) wsumL[wv] = inc;
        __syncthreads();
        unsigned woff = 0;
        for (int i = 0; i < wv; ++i) woff += wsumL[i];
        gbase[t] = woff + inc - sum;
        if (t == 255) Ush = woff + inc;
        __syncthreads();
    }
    const unsigned U = Ush;
    // ---- leaders: global rank by popcount-walk; write SD + ids ----
#pragma unroll
    for (int q = 0; q < 2; ++q) {
        int s = q * 256 + t;
        unsigned ge = gel[s];
        if (ge & 0x8000u) {
            unsigned g = ge & 0x7fffu;
            unsigned v = voc[s];
            unsigned key = v * 32u + (unsigned)b;
            unsigned w = key >> 5;
            unsigned c = w / CH;
            unsigned rank = gbase[c];
            for (unsigned j = c * CH; j < w; ++j)
                rank += (unsigned)__popc(aload(&bitmap[j]));
            rank += (unsigned)__popc(aload(&bitmap[w]) & ((1u << (key & 31u)) - 1u));
            SD[rank] = ((unsigned)b << 19) | (gstart[g] << 10) | gcnt[g];
            out_ids[2 * rank + 0] = (float)v;
            out_ids[2 * rank + 1] = (float)b;
        }
    }
    // ---- pad slots >= U ----
    for (int u = (int)U + b * 256 + t; u < NELEM; u += 32 * 256) {
        SD[u] = 0u;
        out_ids[2 * u + 0] = 0.0f;
        out_ids[2 * u + 1] = 0.0f;
    }
}

// ===========================================================================
// K2: MFMA fused kernel (proven R10). 1024 blocks x 256 thr, 16 rows/block.
// ===========================================================================
#define FBM 16
__global__ __launch_bounds__(256) void fused_kernel(
    const unsigned* __restrict__ Gb,
    const unsigned* __restrict__ SD,
    const unsigned short* __restrict__ WtG,
    const float* __restrict__ emb,
    const float* __restrict__ b1,
    const float* __restrict__ enc,
    float* __restrict__ out_enc) {
    __shared__ char smem[20736];

    const int t = threadIdx.x;
    const int u0 = blockIdx.x * FBM;
    const int l = t & 63;
    const int w = t >> 6;

    const int ar = t >> 4;
    const int ak4 = t & 15;
    const unsigned sdw = SD[u0 + ar];
    const int lenA = (int)(sdw & 1023u);
    const unsigned embBase = (sdw >> 19) << 9;
    const unsigned gb0 = embBase + ((sdw >> 10) & 511u);

    f32x4 acc0 = {0.f, 0.f, 0.f, 0.f};
    f32x4 acc1 = {0.f, 0.f, 0.f, 0.f};

    for (int kk = 0; kk < DIN; kk += 64) {
        __syncthreads();
        {
            float s0 = 0.f, s1 = 0.f, s2 = 0.f, s3 = 0.f;
            const float* base = emb + (size_t)(kk + ak4 * 4);
            for (int p = 0; p < lenA; ++p) {
                unsigned idx = embBase + (Gb[gb0 + p] & 511u);
                const float4 e4 = *(const float4*)(base + (size_t)idx * DIN);
                s0 += e4.x; s1 += e4.y; s2 += e4.z; s3 += e4.w;
            }
            uint2 packed;
            packed.x = f2bf(s0) | (f2bf(s1) << 16);
            packed.y = f2bf(s2) | (f2bf(s3) << 16);
            *(uint2*)(smem + ar * 144 + ak4 * 8) = packed;
        }
        {
#pragma unroll
            for (int i = 0; i < 4; ++i) {
                int q = t + i * 256;
                int c = q >> 3;
                int uo = q & 7;
                uint4 dv = *(const uint4*)(WtG + (size_t)c * DIN + kk + uo * 8);
                *(uint4*)(smem + 2304 + c * 144 + uo * 16) = dv;
            }
        }
        __syncthreads();
        {
            const int arow = l & 15;
            const int ull = l >> 4;
#pragma unroll
            for (int kf = 0; kf < 2; ++kf) {
                short8 aF = *(const short8*)(smem + arow * 144 + kf * 64 + ull * 16);
                short8 bF0 = *(const short8*)(smem + 2304 + (w * 32 + arow) * 144 + kf * 64 + ull * 16);
                short8 bF1 = *(const short8*)(smem + 2304 + (w * 32 + 16 + arow) * 144 + kf * 64 + ull * 16);
                acc0 = __builtin_amdgcn_mfma_f32_16x16x32_bf16(aF, bF0, acc0, 0, 0, 0);
                acc1 = __builtin_amdgcn_mfma_f32_16x16x32_bf16(aF, bF1, acc1, 0, 0, 0);
            }
        }
    }
    __syncthreads();
    {
        float* Hs = (float*)smem;
        const int col0 = w * 32 + (l & 15);
        const int rbase = (l >> 4) * 4;
#pragma unroll
        for (int reg = 0; reg < 4; ++reg) {
            Hs[(rbase + reg) * 132 + col0] = tanhf(acc0[reg] + b1[col0]);
            Hs[(rbase + reg) * 132 + col0 + 16] = tanhf(acc1[reg] + b1[col0 + 16]);
        }
    }
    __syncthreads();
    {
        const float* Hs = (const float*)smem;
        const int r = t >> 4;
        const int g = t & 15;
        const int u = u0 + r;
        const unsigned sdw2 = SD[u];
        unsigned vocab = 0;
        if (sdw2 & 1023u)
            vocab = Gb[((sdw2 >> 19) << 9) + ((sdw2 >> 10) & 511u)] >> 9;
        const float4* wrow = (const float4*)(enc + (size_t)vocab * (DMID * DOUT));
        float ax = 0.f, ay = 0.f, az = 0.f, aw = 0.f;
#pragma unroll
        for (int jj = 0; jj < 8; ++jj) {
            int j = jj * 16 + g;
            float4 w4 = wrow[j];
            float hv = Hs[r * 132 + j];
            ax += hv * w4.x; ay += hv * w4.y; az += hv * w4.z; aw += hv * w4.w;
        }
#pragma unroll
        for (int off = 1; off < 16; off <<= 1) {
            ax += __shfl_xor(ax, off);
            ay += __shfl_xor(ay, off);
            az += __shfl_xor(az, off);
            aw += __shfl_xor(aw, off);
        }
        if (g == 0) {
            float4 o;
            o.x = 1.f / (1.f + expf(-ax));
            o.y = 1.f / (1.f + expf(-ay));
            o.z = 1.f / (1.f + expf(-az));
            o.w = 1.f / (1.f + expf(-aw));
            *(float4*)(out_enc + (size_t)u * 4) = o;
        }
    }
}

// ===========================================================================
// FALLBACK (proven R6): single-block LDS sort + transpose + RS-based fused.
// ===========================================================================
#define SORT_SMEM (65536 + 65536 + 4096 + 64)

__global__ __launch_bounds__(1024) void sort_transpose_kernel(
    const int* __restrict__ vocab_ids,
    const float* __restrict__ W1,
    unsigned int* __restrict__ G,
    unsigned short* __restrict__ RS,
    unsigned short* __restrict__ WtG,
    float* __restrict__ out_ids) {
    const int t = threadIdx.x;
    if (blockIdx.x != 0) {
        int idx = (blockIdx.x - 1) * 1024 + t;
        if (idx < DMID * DIN) {
            int c = idx / DIN;
            int k = idx - c * DIN;
            WtG[idx] = (unsigned short)f2bf(W1[k * DMID + c]);
        }
        return;
    }
    extern __shared__ char smem[];
    unsigned* Gs     = (unsigned*)smem;
    unsigned* histDM = (unsigned*)(smem + 65536);
    unsigned* sums   = (unsigned*)(smem + 131072);
    unsigned* totalU = (unsigned*)(smem + 135168);
    for (int e = t; e < NELEM; e += 1024)
        Gs[e] = ((unsigned)vocab_ids[e] << 14) | (unsigned)e;
    __syncthreads();
    for (int pass = 0; pass < 6; ++pass) {
        const int shift = 9 + pass * 4;
        unsigned v[16];
#pragma unroll
        for (int i = 0; i < 16; ++i) v[i] = Gs[t * 16 + i];
#pragma unroll
        for (int d = 0; d < 16; ++d) histDM[d * 1024 + t] = 0;
#pragma unroll
        for (int i = 0; i < 16; ++i) histDM[((v[i] >> shift) & 15u) * 1024 + t] += 1;
        __syncthreads();
        unsigned lex[16]; unsigned run = 0;
#pragma unroll
        for (int i = 0; i < 16; ++i) { unsigned x = histDM[t * 16 + i]; lex[i] = run; run += x; }
        sums[t] = run;
        __syncthreads();
        if (t < 64) {
            unsigned s[16]; unsigned tot = 0;
#pragma unroll
            for (int i = 0; i < 16; ++i) { unsigned x = sums[t * 16 + i]; s[i] = tot; tot += x; }
            unsigned incv = tot;
#pragma unroll
            for (int off = 1; off < 64; off <<= 1) {
                unsigned y = __shfl_up(incv, off);
                if (t >= off) incv += y;
            }
            unsigned excl = incv - tot;
#pragma unroll
            for (int i = 0; i < 16; ++i) sums[t * 16 + i] = excl + s[i];
        }
        __syncthreads();
#pragma unroll
        for (int i = 0; i < 16; ++i) histDM[t * 16 + i] = sums[t] + lex[i];
        __syncthreads();
        unsigned mycnt[16];
#pragma unroll
        for (int d = 0; d < 16; ++d) mycnt[d] = histDM[d * 1024 + t];
#pragma unroll
        for (int i = 0; i < 16; ++i) {
            unsigned d = (v[i] >> shift) & 15u;
            Gs[mycnt[d]++] = v[i];
        }
        __syncthreads();
    }
    unsigned v[16];
#pragma unroll
    for (int i = 0; i < 16; ++i) v[i] = Gs[t * 16 + i];
    unsigned pk = (t == 0) ? 0xFFFFFFFFu : (Gs[t * 16 - 1] >> 9);
    unsigned fm = 0;
#pragma unroll
    for (int i = 0; i < 16; ++i) {
        unsigned key = v[i] >> 9;
        if (key != pk) fm |= (1u << i);
        pk = key;
    }
    sums[t] = (unsigned)__popc(fm);
    __syncthreads();
    if (t < 64) {
        unsigned s[16]; unsigned tot = 0;
#pragma unroll
        for (int i = 0; i < 16; ++i) { unsigned x = sums[t * 16 + i]; s[i] = tot; tot += x; }
        unsigned incv = tot;
#pragma unroll
        for (int off = 1; off < 64; off <<= 1) {
            unsigned y = __shfl_up(incv, off);
            if (t >= off) incv += y;
        }
        unsigned excl = incv - tot;
#pragma unroll
        for (int i = 0; i < 16; ++i) sums[t * 16 + i] = excl + s[i];
        if (t == 63) *totalU = incv;
    }
    __syncthreads();
    unsigned r = sums[t];
#pragma unroll
    for (int i = 0; i < 16; ++i) {
        if (fm & (1u << i)) {
            RS[r] = (unsigned short)(t * 16 + i);
            out_ids[2 * r + 0] = (float)(v[i] >> 14);
            out_ids[2 * r + 1] = (float)((v[i] >> 9) & 31u);
            ++r;
        }
    }
    const unsigned U = *totalU;
    for (int u = t; u < NELEM; u += 1024) {
        if ((unsigned)u >= U) {
            RS[u] = (unsigned short)NELEM;
            out_ids[2 * u + 0] = 0.0f;
            out_ids[2 * u + 1] = 0.0f;
        }
        G[u] = Gs[u];
    }
    if (t == 0) RS[NELEM] = (unsigned short)NELEM;
}

__global__ __launch_bounds__(256) void fused_kernel_rs(
    const unsigned* __restrict__ G,
    const unsigned short* __restrict__ RS,
    const unsigned short* __restrict__ WtG,
    const float* __restrict__ emb,
    const float* __restrict__ b1,
    const float* __restrict__ enc,
    float* __restrict__ out_enc) {
    __shared__ char smem[20736];
    const int t = threadIdx.x;
    const int u0 = blockIdx.x * FBM;
    const int l = t & 63;
    const int w = t >> 6;
    const int ar = t >> 4;
    const int ak4 = t & 15;
    const int rs_a = (int)RS[u0 + ar];
    const int re_a = (int)RS[u0 + ar + 1];
    f32x4 acc0 = {0.f, 0.f, 0.f, 0.f};
    f32x4 acc1 = {0.f, 0.f, 0.f, 0.f};
    for (int kk = 0; kk < DIN; kk += 64) {
        __syncthreads();
        {
            float s0 = 0.f, s1 = 0.f, s2 = 0.f, s3 = 0.f;
            const float* base = emb + (size_t)(kk + ak4 * 4);
            for (int p = rs_a; p < re_a; ++p) {
                unsigned idx = G[p] & 16383u;
                const float4 e4 = *(const float4*)(base + (size_t)idx * DIN);
                s0 += e4.x; s1 += e4.y; s2 += e4.z; s3 += e4.w;
            }
            uint2 packed;
            packed.x = f2bf(s0) | (f2bf(s1) << 16);
            packed.y = f2bf(s2) | (f2bf(s3) << 16);
            *(uint2*)(smem + ar * 144 + ak4 * 8) = packed;
        }
        {
#pragma unroll
            for (int i = 0; i < 4; ++i) {
                int q = t + i * 256;
                int c = q >> 3;
                int uo = q & 7;
                uint4 dv = *(const uint4*)(WtG + (size_t)c * DIN + kk + uo * 8);
                *(uint4*)(smem + 2304 + c * 144 + uo * 16) = dv;
            }
        }
        __syncthreads();
        {
            const int arow = l & 15;
            const int ull = l >> 4;
#pragma unroll
            for (int kf = 0; kf < 2; ++kf) {
                short8 aF = *(const short8*)(smem + arow * 144 + kf * 64 + ull * 16);
                short8 bF0 = *(const short8*)(smem + 2304 + (w * 32 + arow) * 144 + kf * 64 + ull * 16);
                short8 bF1 = *(const short8*)(smem + 2304 + (w * 32 + 16 + arow) * 144 + kf * 64 + ull * 16);
                acc0 = __builtin_amdgcn_mfma_f32_16x16x32_bf16(aF, bF0, acc0, 0, 0, 0);
                acc1 = __builtin_amdgcn_mfma_f32_16x16x32_bf16(aF, bF1, acc1, 0, 0, 0);
            }
        }
    }
    __syncthreads();
    {
        float* Hs = (float*)smem;
        const int col0 = w * 32 + (l & 15);
        const int rbase = (l >> 4) * 4;
#pragma unroll
        for (int reg = 0; reg < 4; ++reg) {
            Hs[(rbase + reg) * 132 + col0] = tanhf(acc0[reg] + b1[col0]);
            Hs[(rbase + reg) * 132 + col0 + 16] = tanhf(acc1[reg] + b1[col0 + 16]);
        }
    }
    __syncthreads();
    {
        const float* Hs = (const float*)smem;
        const int r = t >> 4;
        const int g = t & 15;
        const int u = u0 + r;
        const int rs = (int)RS[u];
        const int re = (int)RS[u + 1];
        unsigned vocab = (rs < re) ? (G[rs] >> 14) : 0u;
        const float4* wrow = (const float4*)(enc + (size_t)vocab * (DMID * DOUT));
        float ax = 0.f, ay = 0.f, az = 0.f, aw = 0.f;
#pragma unroll
        for (int jj = 0; jj < 8; ++jj) {
            int j = jj * 16 + g;
            float4 w4 = wrow[j];
            float hv = Hs[r * 132 + j];
            ax += hv * w4.x; ay += hv * w4.y; az += hv * w4.z; aw += hv * w4.w;
        }
#pragma unroll
        for (int off = 1; off < 16; off <<= 1) {
            ax += __shfl_xor(ax, off);
            ay += __shfl_xor(ay, off);
            az += __shfl_xor(az, off);
            aw += __shfl_xor(aw, off);
        }
        if (g == 0) {
            float4 o;
            o.x = 1.f / (1.f + expf(-ax));
            o.y = 1.f / (1.f + expf(-ay));
            o.z = 1.f / (1.f + expf(-az));
            o.w = 1.f / (1.f + expf(-aw));
            *(float4*)(out_enc + (size_t)u * 4) = o;
        }
    }
}

// ---------------------------------------------------------------------------
extern "C" void kernel_launch(void* const* d_in, const int* in_sizes, int n_in,
                              void* d_out, int out_size, void* d_ws, size_t ws_size,
                              hipStream_t stream) {
    const int*   vocab_ids = (const int*)d_in[0];
    const float* emb       = (const float*)d_in[1];
    const float* W1        = (const float*)d_in[2];
    const float* b1        = (const float*)d_in[3];
    const float* enc       = (const float*)d_in[4];
    float* out = (float*)d_out;
    float* out_ids = out;
    float* out_enc = out + NELEM * 2;
    char* ws = (char*)d_ws;

    if (ws_size >= FAST3_WS) {
        unsigned*       Gb     = (unsigned*)(ws + 0);
        unsigned*       SD     = (unsigned*)(ws + 65536);
        unsigned short* WtG    = (unsigned short*)(ws + 131072);
        unsigned*       bitmap = (unsigned*)(ws + 327680);
        unsigned*       bar    = (unsigned*)(ws + 727680);

        hipMemsetAsync(bitmap, 0, 400064, stream);   // bitmap + barrier counter
        group2_kernel<<<32, 256, 0, stream>>>(vocab_ids, W1, Gb, SD, WtG,
                                              bitmap, bar, out_ids);
        fused_kernel<<<NELEM / FBM, 256, 0, stream>>>(Gb, SD, WtG, emb, b1, enc, out_enc);
    } else {
        unsigned int*   G   = (unsigned int*)(ws);
        unsigned short* RS  = (unsigned short*)(ws + 65536);
        unsigned short* WtG = (unsigned short*)(ws + 98432);

        hipFuncSetAttribute((const void*)sort_transpose_kernel,
                            hipFuncAttributeMaxDynamicSharedMemorySize, SORT_SMEM);
        sort_transpose_kernel<<<1 + 96, 1024, SORT_SMEM, stream>>>(
            vocab_ids, W1, G, RS, WtG, out_ids);
        fused_kernel_rs<<<NELEM / FBM, 256, 0, stream>>>(G, RS, WtG, emb, b1, enc, out_enc);
    }
}

// Round 12
// 100.446 us; speedup vs baseline: 2.5058x; 2.5058x over previous
//
#include <hip/hip_runtime.h>
#include <hip/hip_bf16.h>

#define NELEM 16384
#define DIN 768
#define DMID 128
#define DOUT 4
#define NBW 100352   // bitmap words, padded to 256*392 (keys < 3.2e6)
#define CH 392       // words per thread-chunk (uint4-aligned: 98 uint4)

typedef __attribute__((ext_vector_type(8))) short short8;
typedef __attribute__((ext_vector_type(4))) float f32x4;

__device__ __forceinline__ unsigned f2bf(float f) {
    unsigned u = __float_as_uint(f);
    return (u + 0x7FFFu + ((u >> 16) & 1u)) >> 16;   // RNE bf16
}
__device__ __forceinline__ void aor(unsigned* p, unsigned v) {
    __hip_atomic_fetch_or(p, v, __ATOMIC_RELAXED, __HIP_MEMORY_SCOPE_AGENT);
}
// threshold barrier; counter zeroed by launch-time memset (proven R9-R11).
// The ACQUIRE makes prior agent-scope atomic writes visible to NORMAL loads.
__device__ __forceinline__ void gbar(unsigned* cnt, unsigned thresh) {
    __syncthreads();
    if (threadIdx.x == 0) {
        __hip_atomic_fetch_add(cnt, 1u, __ATOMIC_ACQ_REL, __HIP_MEMORY_SCOPE_AGENT);
        while (__hip_atomic_load(cnt, __ATOMIC_RELAXED, __HIP_MEMORY_SCOPE_AGENT) < thresh)
            __builtin_amdgcn_s_sleep(1);
        (void)__hip_atomic_load(cnt, __ATOMIC_ACQUIRE, __HIP_MEMORY_SCOPE_AGENT);
    }
    __syncthreads();
}
__device__ __forceinline__ unsigned wscan_inc(unsigned x, int lane) {
    unsigned inc = x;
#pragma unroll
    for (int off = 1; off < 64; off <<= 1) {
        unsigned y = __shfl_up(inc, off);
        if (lane >= off) inc += y;
    }
    return inc;
}

// ===========================================================================
// FAST3 ws layout:
//   Gb@0(64K) SD@65536(64K) WtG@131072(192K) bitmap@327680(401408) bar@729088
//   total 729152.  Memset zeroes [bitmap, bar+64) = 401472 B.
// Gb word = vocab<<9 | s (grouped per batch row, vocab-ascending)
// SD[u]   = b<<19 | start<<10 | len
// ===========================================================================
#define FAST3_WS 729152

// K1: 32 blocks (one per batch row) x 256 threads. ONE global barrier.
__global__ __launch_bounds__(256) void group2_kernel(
    const int* __restrict__ vocab_ids, const float* __restrict__ W1,
    unsigned* __restrict__ Gb, unsigned* __restrict__ SD,
    unsigned short* __restrict__ WtG, unsigned* __restrict__ bitmap,
    unsigned* __restrict__ bar, float* __restrict__ out_ids) {
    __shared__ unsigned lbm[4096];       // 16 KB row vocab bitmap (2^17 bits)
    __shared__ unsigned voc[512];
    __shared__ unsigned short gel[512];  // group idx per element (+leader flag)
    __shared__ unsigned gcnt[512];
    __shared__ unsigned gstart[512];
    __shared__ unsigned part[256];
    __shared__ unsigned gbase[256];
    __shared__ unsigned wsumL[4];
    __shared__ unsigned Ush;

    const int t = threadIdx.x;
    const int b = blockIdx.x;
    const int lane = t & 63;
    const int wv = t >> 6;

    // ---- W1^T -> bf16 (coalesced reads; 3072 elems per block) ----
#pragma unroll
    for (int i = 0; i < 12; ++i) {
        int j = b * 3072 + i * 256 + t;   // 0..98303
        int k = j >> 7, c = j & 127;
        WtG[c * DIN + k] = (unsigned short)f2bf(W1[j]);
    }

    // ---- load row, mark GLOBAL bitmap (atomic, idempotent), zero LDS ----
#pragma unroll
    for (int i = 0; i < 16; ++i) lbm[t + 256 * i] = 0;
    gcnt[t] = 0; gcnt[t + 256] = 0;
#pragma unroll
    for (int q = 0; q < 2; ++q) {
        int s = q * 256 + t;
        unsigned v = (unsigned)vocab_ids[b * 512 + s];
        voc[s] = v;
        unsigned key = v * 32u + (unsigned)b;
        aor(&bitmap[key >> 5], 1u << (key & 31u));
    }
    __syncthreads();
    // ---- local bitmap mark ----
#pragma unroll
    for (int q = 0; q < 2; ++q) {
        unsigned v = voc[q * 256 + t];
        atomicOr(&lbm[v >> 5], 1u << (v & 31u));
    }
    __syncthreads();
    // ---- local chunk-scan (16 words/thread) -> part[] = exclusive base ----
    {
        unsigned sum = 0;
#pragma unroll
        for (int j = 0; j < 16; ++j) sum += (unsigned)__popc(lbm[t * 16 + j]);
        unsigned inc = wscan_inc(sum, lane);
        if (lane == 63) wsumL[wv] = inc;
        __syncthreads();
        unsigned woff = 0;
        for (int i = 0; i < wv; ++i) woff += wsumL[i];
        part[t] = woff + inc - sum;
        __syncthreads();
    }
    // ---- per-element group index g; count group sizes ----
#pragma unroll
    for (int q = 0; q < 2; ++q) {
        int s = q * 256 + t;
        unsigned v = voc[s];
        unsigned lw = v >> 5, c = lw >> 4;
        unsigned g = part[c];
        for (unsigned j = c * 16; j < lw; ++j) g += (unsigned)__popc(lbm[j]);
        g += (unsigned)__popc(lbm[lw] & ((1u << (v & 31u)) - 1u));
        gel[s] = (unsigned short)g;
        atomicAdd(&gcnt[g], 1u);                      // counts only: deterministic
    }
    __syncthreads();
    // ---- exclusive scan gcnt[512] -> gstart ----
    {
        unsigned a = gcnt[2 * t], b2 = gcnt[2 * t + 1];
        unsigned pair = a + b2;
        unsigned inc = wscan_inc(pair, lane);
        if (lane == 63) wsumL[wv] = inc;
        __syncthreads();
        unsigned woff = 0;
        for (int i = 0; i < wv; ++i) woff += wsumL[i];
        unsigned excl = woff + inc - pair;
        gstart[2 * t] = excl;
        gstart[2 * t + 1] = excl + a;
    }
    __syncthreads();
    // ---- deterministic member index + grouped Gb write + leader flag ----
#pragma unroll
    for (int q = 0; q < 2; ++q) {
        int s = q * 256 + t;
        unsigned g = gel[s];
        unsigned m = 0;
        if (gcnt[g] > 1) {                            // rare (~1.3/row)
            unsigned v = voc[s];
            for (int j = 0; j < s; ++j) if (voc[j] == v) ++m;
        }
        Gb[b * 512 + gstart[g] + m] = (voc[s] << 9) | (unsigned)s;
        if (m == 0) gel[s] = (unsigned short)(g | 0x8000u);
    }

    gbar(bar, 32);   // the ONE global barrier: global bitmap complete

    // ---- redundant global chunk-scan with CACHED uint4 loads ----
    {
        const uint4* bm4 = (const uint4*)bitmap;
        unsigned sum = 0;
        const int q0 = t * (CH / 4);
#pragma unroll 7
        for (int j = 0; j < CH / 4; ++j) {
            uint4 x = bm4[q0 + j];
            sum += (unsigned)(__popc(x.x) + __popc(x.y) + __popc(x.z) + __popc(x.w));
        }
        unsigned inc = wscan_inc(sum, lane);
        if (lane == 63) wsumL[wv] = inc;
        __syncthreads();
        unsigned woff = 0;
        for (int i = 0; i < wv; ++i) woff += wsumL[i];
        gbase[t] = woff + inc - sum;
        if (t == 255) Ush = woff + inc;
        __syncthreads();
    }
    const unsigned U = Ush;
    // ---- leaders: global rank via cached popcount-walk; write SD + ids ----
#pragma unroll
    for (int q = 0; q < 2; ++q) {
        int s = q * 256 + t;
        unsigned ge = gel[s];
        if (ge & 0x8000u) {
            unsigned g = ge & 0x7fffu;
            unsigned v = voc[s];
            unsigned key = v * 32u + (unsigned)b;
            unsigned w = key >> 5;
            unsigned c = w / CH;
            unsigned rank = gbase[c];
            for (unsigned j = c * CH; j < w; ++j)
                rank += (unsigned)__popc(bitmap[j]);
            rank += (unsigned)__popc(bitmap[w] & ((1u << (key & 31u)) - 1u));
            SD[rank] = ((unsigned)b << 19) | (gstart[g] << 10) | gcnt[g];
            out_ids[2 * rank + 0] = (float)v;
            out_ids[2 * rank + 1] = (float)b;
        }
    }
    // ---- pad slots >= U ----
    for (int u = (int)U + b * 256 + t; u < NELEM; u += 32 * 256) {
        SD[u] = 0u;
        out_ids[2 * u + 0] = 0.0f;
        out_ids[2 * u + 1] = 0.0f;
    }
}

// ===========================================================================
// K2: MFMA fused kernel (proven R10/R11). 1024 blocks x 256 thr, 16 rows.
// ===========================================================================
#define FBM 16
__global__ __launch_bounds__(256) void fused_kernel(
    const unsigned* __restrict__ Gb,
    const unsigned* __restrict__ SD,
    const unsigned short* __restrict__ WtG,
    const float* __restrict__ emb,
    const float* __restrict__ b1,
    const float* __restrict__ enc,
    float* __restrict__ out_enc) {
    __shared__ char smem[20736];

    const int t = threadIdx.x;
    const int u0 = blockIdx.x * FBM;
    const int l = t & 63;
    const int w = t >> 6;

    const int ar = t >> 4;
    const int ak4 = t & 15;
    const unsigned sdw = SD[u0 + ar];
    const int lenA = (int)(sdw & 1023u);
    const unsigned embBase = (sdw >> 19) << 9;
    const unsigned gb0 = embBase + ((sdw >> 10) & 511u);

    f32x4 acc0 = {0.f, 0.f, 0.f, 0.f};
    f32x4 acc1 = {0.f, 0.f, 0.f, 0.f};

    for (int kk = 0; kk < DIN; kk += 64) {
        __syncthreads();
        {
            float s0 = 0.f, s1 = 0.f, s2 = 0.f, s3 = 0.f;
            const float* base = emb + (size_t)(kk + ak4 * 4);
            for (int p = 0; p < lenA; ++p) {
                unsigned idx = embBase + (Gb[gb0 + p] & 511u);
                const float4 e4 = *(const float4*)(base + (size_t)idx * DIN);
                s0 += e4.x; s1 += e4.y; s2 += e4.z; s3 += e4.w;
            }
            uint2 packed;
            packed.x = f2bf(s0) | (f2bf(s1) << 16);
            packed.y = f2bf(s2) | (f2bf(s3) << 16);
            *(uint2*)(smem + ar * 144 + ak4 * 8) = packed;
        }
        {
#pragma unroll
            for (int i = 0; i < 4; ++i) {
                int q = t + i * 256;
                int c = q >> 3;
                int uo = q & 7;
                uint4 dv = *(const uint4*)(WtG + (size_t)c * DIN + kk + uo * 8);
                *(uint4*)(smem + 2304 + c * 144 + uo * 16) = dv;
            }
        }
        __syncthreads();
        {
            const int arow = l & 15;
            const int ull = l >> 4;
#pragma unroll
            for (int kf = 0; kf < 2; ++kf) {
                short8 aF = *(const short8*)(smem + arow * 144 + kf * 64 + ull * 16);
                short8 bF0 = *(const short8*)(smem + 2304 + (w * 32 + arow) * 144 + kf * 64 + ull * 16);
                short8 bF1 = *(const short8*)(smem + 2304 + (w * 32 + 16 + arow) * 144 + kf * 64 + ull * 16);
                acc0 = __builtin_amdgcn_mfma_f32_16x16x32_bf16(aF, bF0, acc0, 0, 0, 0);
                acc1 = __builtin_amdgcn_mfma_f32_16x16x32_bf16(aF, bF1, acc1, 0, 0, 0);
            }
        }
    }
    __syncthreads();
    {
        float* Hs = (float*)smem;
        const int col0 = w * 32 + (l & 15);
        const int rbase = (l >> 4) * 4;
#pragma unroll
        for (int reg = 0; reg < 4; ++reg) {
            Hs[(rbase + reg) * 132 + col0] = tanhf(acc0[reg] + b1[col0]);
            Hs[(rbase + reg) * 132 + col0 + 16] = tanhf(acc1[reg] + b1[col0 + 16]);
        }
    }
    __syncthreads();
    {
        const float* Hs = (const float*)smem;
        const int r = t >> 4;
        const int g = t & 15;
        const int u = u0 + r;
        const unsigned sdw2 = SD[u];
        unsigned vocab = 0;
        if (sdw2 & 1023u)
            vocab = Gb[((sdw2 >> 19) << 9) + ((sdw2 >> 10) & 511u)] >> 9;
        const float4* wrow = (const float4*)(enc + (size_t)vocab * (DMID * DOUT));
        float ax = 0.f, ay = 0.f, az = 0.f, aw = 0.f;
#pragma unroll
        for (int jj = 0; jj < 8; ++jj) {
            int j = jj * 16 + g;
            float4 w4 = wrow[j];
            float hv = Hs[r * 132 + j];
            ax += hv * w4.x; ay += hv * w4.y; az += hv * w4.z; aw += hv * w4.w;
        }
#pragma unroll
        for (int off = 1; off < 16; off <<= 1) {
            ax += __shfl_xor(ax, off);
            ay += __shfl_xor(ay, off);
            az += __shfl_xor(az, off);
            aw += __shfl_xor(aw, off);
        }
        if (g == 0) {
            float4 o;
            o.x = 1.f / (1.f + expf(-ax));
            o.y = 1.f / (1.f + expf(-ay));
            o.z = 1.f / (1.f + expf(-az));
            o.w = 1.f / (1.f + expf(-aw));
            *(float4*)(out_enc + (size_t)u * 4) = o;
        }
    }
}

// ===========================================================================
// FALLBACK (proven R6): single-block LDS sort + transpose + RS-based fused.
// ===========================================================================
#define SORT_SMEM (65536 + 65536 + 4096 + 64)

__global__ __launch_bounds__(1024) void sort_transpose_kernel(
    const int* __restrict__ vocab_ids,
    const float* __restrict__ W1,
    unsigned int* __restrict__ G,
    unsigned short* __restrict__ RS,
    unsigned short* __restrict__ WtG,
    float* __restrict__ out_ids) {
    const int t = threadIdx.x;
    if (blockIdx.x != 0) {
        int idx = (blockIdx.x - 1) * 1024 + t;
        if (idx < DMID * DIN) {
            int c = idx / DIN;
            int k = idx - c * DIN;
            WtG[idx] = (unsigned short)f2bf(W1[k * DMID + c]);
        }
        return;
    }
    extern __shared__ char smem[];
    unsigned* Gs     = (unsigned*)smem;
    unsigned* histDM = (unsigned*)(smem + 65536);
    unsigned* sums   = (unsigned*)(smem + 131072);
    unsigned* totalU = (unsigned*)(smem + 135168);
    for (int e = t; e < NELEM; e += 1024)
        Gs[e] = ((unsigned)vocab_ids[e] << 14) | (unsigned)e;
    __syncthreads();
    for (int pass = 0; pass < 6; ++pass) {
        const int shift = 9 + pass * 4;
        unsigned v[16];
#pragma unroll
        for (int i = 0; i < 16; ++i) v[i] = Gs[t * 16 + i];
#pragma unroll
        for (int d = 0; d < 16; ++d) histDM[d * 1024 + t] = 0;
#pragma unroll
        for (int i = 0; i < 16; ++i) histDM[((v[i] >> shift) & 15u) * 1024 + t] += 1;
        __syncthreads();
        unsigned lex[16]; unsigned run = 0;
#pragma unroll
        for (int i = 0; i < 16; ++i) { unsigned x = histDM[t * 16 + i]; lex[i] = run; run += x; }
        sums[t] = run;
        __syncthreads();
        if (t < 64) {
            unsigned s[16]; unsigned tot = 0;
#pragma unroll
            for (int i = 0; i < 16; ++i) { unsigned x = sums[t * 16 + i]; s[i] = tot; tot += x; }
            unsigned incv = tot;
#pragma unroll
            for (int off = 1; off < 64; off <<= 1) {
                unsigned y = __shfl_up(incv, off);
                if (t >= off) incv += y;
            }
            unsigned excl = incv - tot;
#pragma unroll
            for (int i = 0; i < 16; ++i) sums[t * 16 + i] = excl + s[i];
        }
        __syncthreads();
#pragma unroll
        for (int i = 0; i < 16; ++i) histDM[t * 16 + i] = sums[t] + lex[i];
        __syncthreads();
        unsigned mycnt[16];
#pragma unroll
        for (int d = 0; d < 16; ++d) mycnt[d] = histDM[d * 1024 + t];
#pragma unroll
        for (int i = 0; i < 16; ++i) {
            unsigned d = (v[i] >> shift) & 15u;
            Gs[mycnt[d]++] = v[i];
        }
        __syncthreads();
    }
    unsigned v[16];
#pragma unroll
    for (int i = 0; i < 16; ++i) v[i] = Gs[t * 16 + i];
    unsigned pk = (t == 0) ? 0xFFFFFFFFu : (Gs[t * 16 - 1] >> 9);
    unsigned fm = 0;
#pragma unroll
    for (int i = 0; i < 16; ++i) {
        unsigned key = v[i] >> 9;
        if (key != pk) fm |= (1u << i);
        pk = key;
    }
    sums[t] = (unsigned)__popc(fm);
    __syncthreads();
    if (t < 64) {
        unsigned s[16]; unsigned tot = 0;
#pragma unroll
        for (int i = 0; i < 16; ++i) { unsigned x = sums[t * 16 + i]; s[i] = tot; tot += x; }
        unsigned incv = tot;
#pragma unroll
        for (int off = 1; off < 64; off <<= 1) {
            unsigned y = __shfl_up(incv, off);
            if (t >= off) incv += y;
        }
        unsigned excl = incv - tot;
#pragma unroll
        for (int i = 0; i < 16; ++i) sums[t * 16 + i] = excl + s[i];
        if (t == 63) *totalU = incv;
    }
    __syncthreads();
    unsigned r = sums[t];
#pragma unroll
    for (int i = 0; i < 16; ++i) {
        if (fm & (1u << i)) {
            RS[r] = (unsigned short)(t * 16 + i);
            out_ids[2 * r + 0] = (float)(v[i] >> 14);
            out_ids[2 * r + 1] = (float)((v[i] >> 9) & 31u);
            ++r;
        }
    }
    const unsigned U = *totalU;
    for (int u = t; u < NELEM; u += 1024) {
        if ((unsigned)u >= U) {
            RS[u] = (unsigned short)NELEM;
            out_ids[2 * u + 0] = 0.0f;
            out_ids[2 * u + 1] = 0.0f;
        }
        G[u] = Gs[u];
    }
    if (t == 0) RS[NELEM] = (unsigned short)NELEM;
}

__global__ __launch_bounds__(256) void fused_kernel_rs(
    const unsigned* __restrict__ G,
    const unsigned short* __restrict__ RS,
    const unsigned short* __restrict__ WtG,
    const float* __restrict__ emb,
    const float* __restrict__ b1,
    const float* __restrict__ enc,
    float* __restrict__ out_enc) {
    __shared__ char smem[20736];
    const int t = threadIdx.x;
    const int u0 = blockIdx.x * FBM;
    const int l = t & 63;
    const int w = t >> 6;
    const int ar = t >> 4;
    const int ak4 = t & 15;
    const int rs_a = (int)RS[u0 + ar];
    const int re_a = (int)RS[u0 + ar + 1];
    f32x4 acc0 = {0.f, 0.f, 0.f, 0.f};
    f32x4 acc1 = {0.f, 0.f, 0.f, 0.f};
    for (int kk = 0; kk < DIN; kk += 64) {
        __syncthreads();
        {
            float s0 = 0.f, s1 = 0.f, s2 = 0.f, s3 = 0.f;
            const float* base = emb + (size_t)(kk + ak4 * 4);
            for (int p = rs_a; p < re_a; ++p) {
                unsigned idx = G[p] & 16383u;
                const float4 e4 = *(const float4*)(base + (size_t)idx * DIN);
                s0 += e4.x; s1 += e4.y; s2 += e4.z; s3 += e4.w;
            }
            uint2 packed;
            packed.x = f2bf(s0) | (f2bf(s1) << 16);
            packed.y = f2bf(s2) | (f2bf(s3) << 16);
            *(uint2*)(smem + ar * 144 + ak4 * 8) = packed;
        }
        {
#pragma unroll
            for (int i = 0; i < 4; ++i) {
                int q = t + i * 256;
                int c = q >> 3;
                int uo = q & 7;
                uint4 dv = *(const uint4*)(WtG + (size_t)c * DIN + kk + uo * 8);
                *(uint4*)(smem + 2304 + c * 144 + uo * 16) = dv;
            }
        }
        __syncthreads();
        {
            const int arow = l & 15;
            const int ull = l >> 4;
#pragma unroll
            for (int kf = 0; kf < 2; ++kf) {
                short8 aF = *(const short8*)(smem + arow * 144 + kf * 64 + ull * 16);
                short8 bF0 = *(const short8*)(smem + 2304 + (w * 32 + arow) * 144 + kf * 64 + ull * 16);
                short8 bF1 = *(const short8*)(smem + 2304 + (w * 32 + 16 + arow) * 144 + kf * 64 + ull * 16);
                acc0 = __builtin_amdgcn_mfma_f32_16x16x32_bf16(aF, bF0, acc0, 0, 0, 0);
                acc1 = __builtin_amdgcn_mfma_f32_16x16x32_bf16(aF, bF1, acc1, 0, 0, 0);
            }
        }
    }
    __syncthreads();
    {
        float* Hs = (float*)smem;
        const int col0 = w * 32 + (l & 15);
        const int rbase = (l >> 4) * 4;
#pragma unroll
        for (int reg = 0; reg < 4; ++reg) {
            Hs[(rbase + reg) * 132 + col0] = tanhf(acc0[reg] + b1[col0]);
            Hs[(rbase + reg) * 132 + col0 + 16] = tanhf(acc1[reg] + b1[col0 + 16]);
        }
    }
    __syncthreads();
    {
        const float* Hs = (const float*)smem;
        const int r = t >> 4;
        const int g = t & 15;
        const int u = u0 + r;
        const int rs = (int)RS[u];
        const int re = (int)RS[u + 1];
        unsigned vocab = (rs < re) ? (G[rs] >> 14) : 0u;
        const float4* wrow = (const float4*)(enc + (size_t)vocab * (DMID * DOUT));
        float ax = 0.f, ay = 0.f, az = 0.f, aw = 0.f;
#pragma unroll
        for (int jj = 0; jj < 8; ++jj) {
            int j = jj * 16 + g;
            float4 w4 = wrow[j];
            float hv = Hs[r * 132 + j];
            ax += hv * w4.x; ay += hv * w4.y; az += hv * w4.z; aw += hv * w4.w;
        }
#pragma unroll
        for (int off = 1; off < 16; off <<= 1) {
            ax += __shfl_xor(ax, off);
            ay += __shfl_xor(ay, off);
            az += __shfl_xor(az, off);
            aw += __shfl_xor(aw, off);
        }
        if (g == 0) {
            float4 o;
            o.x = 1.f / (1.f + expf(-ax));
            o.y = 1.f / (1.f + expf(-ay));
            o.z = 1.f / (1.f + expf(-az));
            o.w = 1.f / (1.f + expf(-aw));
            *(float4*)(out_enc + (size_t)u * 4) = o;
        }
    }
}

// ---------------------------------------------------------------------------
extern "C" void kernel_launch(void* const* d_in, const int* in_sizes, int n_in,
                              void* d_out, int out_size, void* d_ws, size_t ws_size,
                              hipStream_t stream) {
    const int*   vocab_ids = (const int*)d_in[0];
    const float* emb       = (const float*)d_in[1];
    const float* W1        = (const float*)d_in[2];
    const float* b1        = (const float*)d_in[3];
    const float* enc       = (const float*)d_in[4];
    float* out = (float*)d_out;
    float* out_ids = out;
    float* out_enc = out + NELEM * 2;
    char* ws = (char*)d_ws;

    if (ws_size >= FAST3_WS) {
        unsigned*       Gb     = (unsigned*)(ws + 0);
        unsigned*       SD     = (unsigned*)(ws + 65536);
        unsigned short* WtG    = (unsigned short*)(ws + 131072);
        unsigned*       bitmap = (unsigned*)(ws + 327680);
        unsigned*       bar    = (unsigned*)(ws + 729088);

        hipMemsetAsync(bitmap, 0, 401472, stream);   // bitmap + barrier counter
        group2_kernel<<<32, 256, 0, stream>>>(vocab_ids, W1, Gb, SD, WtG,
                                              bitmap, bar, out_ids);
        fused_kernel<<<NELEM / FBM, 256, 0, stream>>>(Gb, SD, WtG, emb, b1, enc, out_enc);
    } else {
        unsigned int*   G   = (unsigned int*)(ws);
        unsigned short* RS  = (unsigned short*)(ws + 65536);
        unsigned short* WtG = (unsigned short*)(ws + 98432);

        hipFuncSetAttribute((const void*)sort_transpose_kernel,
                            hipFuncAttributeMaxDynamicSharedMemorySize, SORT_SMEM);
        sort_transpose_kernel<<<1 + 96, 1024, SORT_SMEM, stream>>>(
            vocab_ids, W1, G, RS, WtG, out_ids);
        fused_kernel_rs<<<NELEM / FBM, 256, 0, stream>>>(G, RS, WtG, emb, b1, enc, out_enc);
    }
}

// Round 13
// 69.637 us; speedup vs baseline: 3.6144x; 1.4424x over previous
//
#include <hip/hip_runtime.h>
#include <hip/hip_bf16.h>

#define NELEM 16384
#define DIN 768
#define DMID 128
#define DOUT 4
#define NBWPAD 114688   // bitmap words padded to 256 threads * 448 words
#define BMBYTES 458752  // NBWPAD * 4

typedef __attribute__((ext_vector_type(8))) short short8;
typedef __attribute__((ext_vector_type(4))) float f32x4;

__device__ __forceinline__ unsigned f2bf(float f) {
    unsigned u = __float_as_uint(f);
    return (u + 0x7FFFu + ((u >> 16) & 1u)) >> 16;   // RNE bf16
}
__device__ __forceinline__ void aor(unsigned* p, unsigned v) {
    __hip_atomic_fetch_or(p, v, __ATOMIC_RELAXED, __HIP_MEMORY_SCOPE_AGENT);
}
__device__ __forceinline__ unsigned wscan_inc(unsigned x, int lane) {
    unsigned inc = x;
#pragma unroll
    for (int off = 1; off < 64; off <<= 1) {
        unsigned y = __shfl_up(inc, off);
        if (lane >= off) inc += y;
    }
    return inc;
}
__device__ __forceinline__ unsigned popc4(uint4 x) {
    return (unsigned)(__popc(x.x) + __popc(x.y) + __popc(x.z) + __popc(x.w));
}

// ===========================================================================
// FAST4 ws layout:
//   Gb@0(64K) SD@65536(64K) WtG@131072(192K) stage@327680(128K)
//   LCnt@458752(128) bitmap@458880(448K)  -> total 917,632
// Gb word = vocab<<9 | s (grouped per batch row, vocab-ascending)
// SD[u]   = b<<19 | start<<10 | len
// stage[b*512+g] = (u64)vocab<<32 | SDvalue ; LCnt[b] = #groups in row b
// ===========================================================================
#define FAST4_WS 917632

// K1: prep. 32 blocks (one per batch row) x 256 threads. No global sync.
__global__ __launch_bounds__(256) void prep_kernel(
    const int* __restrict__ vocab_ids, const float* __restrict__ W1,
    unsigned* __restrict__ Gb, unsigned short* __restrict__ WtG,
    unsigned* __restrict__ bitmap, unsigned long long* __restrict__ stage,
    unsigned* __restrict__ LCnt) {
    __shared__ unsigned lbm[4096];       // 16 KB row vocab bitmap (2^17 bits)
    __shared__ unsigned voc[512];
    __shared__ unsigned short gel[512];
    __shared__ unsigned gcnt[512];
    __shared__ unsigned gstart[512];
    __shared__ unsigned part[256];
    __shared__ unsigned wsumL[4];

    const int t = threadIdx.x;
    const int b = blockIdx.x;
    const int lane = t & 63;
    const int wv = t >> 6;

    // ---- W1^T -> bf16 (coalesced reads) ----
#pragma unroll
    for (int i = 0; i < 12; ++i) {
        int j = b * 3072 + i * 256 + t;   // 0..98303
        int k = j >> 7, c = j & 127;
        WtG[c * DIN + k] = (unsigned short)f2bf(W1[j]);
    }

    // ---- load row, mark GLOBAL bitmap (atomic, idempotent), zero LDS ----
#pragma unroll
    for (int i = 0; i < 16; ++i) lbm[t + 256 * i] = 0;
    gcnt[t] = 0; gcnt[t + 256] = 0;
#pragma unroll
    for (int q = 0; q < 2; ++q) {
        int s = q * 256 + t;
        unsigned v = (unsigned)vocab_ids[b * 512 + s];
        voc[s] = v;
        unsigned key = v * 32u + (unsigned)b;
        aor(&bitmap[key >> 5], 1u << (key & 31u));
    }
    __syncthreads();
    // ---- local bitmap mark ----
#pragma unroll
    for (int q = 0; q < 2; ++q) {
        unsigned v = voc[q * 256 + t];
        atomicOr(&lbm[v >> 5], 1u << (v & 31u));
    }
    __syncthreads();
    // ---- local chunk-scan (16 words/thread) -> part[]; LCnt = total groups ----
    {
        unsigned sum = 0;
#pragma unroll
        for (int j = 0; j < 16; ++j) sum += (unsigned)__popc(lbm[t * 16 + j]);
        unsigned inc = wscan_inc(sum, lane);
        if (lane == 63) wsumL[wv] = inc;
        __syncthreads();
        unsigned woff = 0;
        for (int i = 0; i < wv; ++i) woff += wsumL[i];
        part[t] = woff + inc - sum;
        if (t == 255) LCnt[b] = woff + inc;
        __syncthreads();
    }
    // ---- per-element group index g; count group sizes ----
#pragma unroll
    for (int q = 0; q < 2; ++q) {
        int s = q * 256 + t;
        unsigned v = voc[s];
        unsigned lw = v >> 5, c = lw >> 4;
        unsigned g = part[c];
        for (unsigned j = c * 16; j < lw; ++j) g += (unsigned)__popc(lbm[j]);
        g += (unsigned)__popc(lbm[lw] & ((1u << (v & 31u)) - 1u));
        gel[s] = (unsigned short)g;
        atomicAdd(&gcnt[g], 1u);                      // counts only: deterministic
    }
    __syncthreads();
    // ---- exclusive scan gcnt[512] -> gstart ----
    {
        unsigned a = gcnt[2 * t], b2 = gcnt[2 * t + 1];
        unsigned pair = a + b2;
        unsigned inc = wscan_inc(pair, lane);
        if (lane == 63) wsumL[wv] = inc;
        __syncthreads();
        unsigned woff = 0;
        for (int i = 0; i < wv; ++i) woff += wsumL[i];
        unsigned excl = woff + inc - pair;
        gstart[2 * t] = excl;
        gstart[2 * t + 1] = excl + a;
    }
    __syncthreads();
    // ---- member index + grouped Gb write + leader staging ----
#pragma unroll
    for (int q = 0; q < 2; ++q) {
        int s = q * 256 + t;
        unsigned g = gel[s];
        unsigned v = voc[s];
        unsigned m = 0;
        if (gcnt[g] > 1) {                            // rare
            for (int j = 0; j < s; ++j) if (voc[j] == v) ++m;
        }
        Gb[b * 512 + gstart[g] + m] = (v << 9) | (unsigned)s;
        if (m == 0) {
            unsigned sdval = ((unsigned)b << 19) | (gstart[g] << 10) | gcnt[g];
            stage[b * 512 + g] = ((unsigned long long)v << 32) | sdval;
        }
    }
}

// K2: rank. 32 blocks x 256 threads. Redundant bitmap scan builds a
// per-16-word prefix table in LDS; leader rank = table + <=4 cached loads.
__global__ __launch_bounds__(256) void rank_kernel(
    const unsigned* __restrict__ bitmap,
    const unsigned long long* __restrict__ stage,
    const unsigned* __restrict__ LCnt,
    unsigned* __restrict__ SD, float* __restrict__ out_ids) {
    __shared__ unsigned pre16[7168];     // 28 KB: global prefix per 16 words
    __shared__ unsigned wsumL[4];
    __shared__ unsigned Ush;

    const int t = threadIdx.x;
    const int b = blockIdx.x;
    const int lane = t & 63;
    const int wv = t >> 6;
    const uint4* bm4 = (const uint4*)bitmap;

    // ---- scan: thread t owns uint4 [t*112, t*112+112) = 28 groups of 16 words
    unsigned locpre[28];
    unsigned run = 0;
    {
        const uint4* my = bm4 + t * 112;
#pragma unroll
        for (int g = 0; g < 28; ++g) {
            locpre[g] = run;
#pragma unroll
            for (int q = 0; q < 4; ++q) run += popc4(my[g * 4 + q]);
        }
        unsigned inc = wscan_inc(run, lane);
        if (lane == 63) wsumL[wv] = inc;
        __syncthreads();
        unsigned woff = 0;
        for (int i = 0; i < wv; ++i) woff += wsumL[i];
        unsigned excl = woff + inc - run;
#pragma unroll
        for (int g = 0; g < 28; ++g) pre16[t * 28 + g] = excl + locpre[g];
        if (t == 255) Ush = woff + inc;
        __syncthreads();
    }
    const unsigned U = Ush;

    // ---- leaders of row b: rank + SD + ids ----
    const unsigned cnt = LCnt[b];
    for (unsigned l = t; l < cnt; l += 256) {
        unsigned long long sv = stage[b * 512 + l];
        unsigned v = (unsigned)(sv >> 32);
        unsigned sdval = (unsigned)sv;
        unsigned key = v * 32u + (unsigned)b;
        unsigned w = key >> 5, bit = key & 31u;
        unsigned rank = pre16[w >> 4];
        const uint4* gp = bm4 + ((w >> 4) << 2);
        unsigned wq = (w >> 2) & 3u;
        for (unsigned q = 0; q < wq; ++q) rank += popc4(gp[q]);
        uint4 x = gp[wq];
        unsigned ww = w & 3u;
        if (ww > 0) rank += (unsigned)__popc(x.x);
        if (ww > 1) rank += (unsigned)__popc(x.y);
        if (ww > 2) rank += (unsigned)__popc(x.z);
        unsigned wword = (ww == 0) ? x.x : (ww == 1) ? x.y : (ww == 2) ? x.z : x.w;
        rank += (unsigned)__popc(wword & ((1u << bit) - 1u));
        SD[rank] = sdval;
        out_ids[2 * rank + 0] = (float)v;
        out_ids[2 * rank + 1] = (float)((sdval >> 19) & 31u);
    }
    // ---- pad slots >= U ----
    for (int u = (int)U + b * 256 + t; u < NELEM; u += 32 * 256) {
        SD[u] = 0u;
        out_ids[2 * u + 0] = 0.0f;
        out_ids[2 * u + 1] = 0.0f;
    }
}

// ===========================================================================
// K3: MFMA fused kernel (proven R10-R12). 1024 blocks x 256 thr, 16 rows.
// ===========================================================================
#define FBM 16
__global__ __launch_bounds__(256) void fused_kernel(
    const unsigned* __restrict__ Gb,
    const unsigned* __restrict__ SD,
    const unsigned short* __restrict__ WtG,
    const float* __restrict__ emb,
    const float* __restrict__ b1,
    const float* __restrict__ enc,
    float* __restrict__ out_enc) {
    __shared__ char smem[20736];

    const int t = threadIdx.x;
    const int u0 = blockIdx.x * FBM;
    const int l = t & 63;
    const int w = t >> 6;

    const int ar = t >> 4;
    const int ak4 = t & 15;
    const unsigned sdw = SD[u0 + ar];
    const int lenA = (int)(sdw & 1023u);
    const unsigned embBase = (sdw >> 19) << 9;
    const unsigned gb0 = embBase + ((sdw >> 10) & 511u);

    f32x4 acc0 = {0.f, 0.f, 0.f, 0.f};
    f32x4 acc1 = {0.f, 0.f, 0.f, 0.f};

    for (int kk = 0; kk < DIN; kk += 64) {
        __syncthreads();
        {
            float s0 = 0.f, s1 = 0.f, s2 = 0.f, s3 = 0.f;
            const float* base = emb + (size_t)(kk + ak4 * 4);
            for (int p = 0; p < lenA; ++p) {
                unsigned idx = embBase + (Gb[gb0 + p] & 511u);
                const float4 e4 = *(const float4*)(base + (size_t)idx * DIN);
                s0 += e4.x; s1 += e4.y; s2 += e4.z; s3 += e4.w;
            }
            uint2 packed;
            packed.x = f2bf(s0) | (f2bf(s1) << 16);
            packed.y = f2bf(s2) | (f2bf(s3) << 16);
            *(uint2*)(smem + ar * 144 + ak4 * 8) = packed;
        }
        {
#pragma unroll
            for (int i = 0; i < 4; ++i) {
                int q = t + i * 256;
                int c = q >> 3;
                int uo = q & 7;
                uint4 dv = *(const uint4*)(WtG + (size_t)c * DIN + kk + uo * 8);
                *(uint4*)(smem + 2304 + c * 144 + uo * 16) = dv;
            }
        }
        __syncthreads();
        {
            const int arow = l & 15;
            const int ull = l >> 4;
#pragma unroll
            for (int kf = 0; kf < 2; ++kf) {
                short8 aF = *(const short8*)(smem + arow * 144 + kf * 64 + ull * 16);
                short8 bF0 = *(const short8*)(smem + 2304 + (w * 32 + arow) * 144 + kf * 64 + ull * 16);
                short8 bF1 = *(const short8*)(smem + 2304 + (w * 32 + 16 + arow) * 144 + kf * 64 + ull * 16);
                acc0 = __builtin_amdgcn_mfma_f32_16x16x32_bf16(aF, bF0, acc0, 0, 0, 0);
                acc1 = __builtin_amdgcn_mfma_f32_16x16x32_bf16(aF, bF1, acc1, 0, 0, 0);
            }
        }
    }
    __syncthreads();
    {
        float* Hs = (float*)smem;
        const int col0 = w * 32 + (l & 15);
        const int rbase = (l >> 4) * 4;
#pragma unroll
        for (int reg = 0; reg < 4; ++reg) {
            Hs[(rbase + reg) * 132 + col0] = tanhf(acc0[reg] + b1[col0]);
            Hs[(rbase + reg) * 132 + col0 + 16] = tanhf(acc1[reg] + b1[col0 + 16]);
        }
    }
    __syncthreads();
    {
        const float* Hs = (const float*)smem;
        const int r = t >> 4;
        const int g = t & 15;
        const int u = u0 + r;
        const unsigned sdw2 = SD[u];
        unsigned vocab = 0;
        if (sdw2 & 1023u)
            vocab = Gb[((sdw2 >> 19) << 9) + ((sdw2 >> 10) & 511u)] >> 9;
        const float4* wrow = (const float4*)(enc + (size_t)vocab * (DMID * DOUT));
        float ax = 0.f, ay = 0.f, az = 0.f, aw = 0.f;
#pragma unroll
        for (int jj = 0; jj < 8; ++jj) {
            int j = jj * 16 + g;
            float4 w4 = wrow[j];
            float hv = Hs[r * 132 + j];
            ax += hv * w4.x; ay += hv * w4.y; az += hv * w4.z; aw += hv * w4.w;
        }
#pragma unroll
        for (int off = 1; off < 16; off <<= 1) {
            ax += __shfl_xor(ax, off);
            ay += __shfl_xor(ay, off);
            az += __shfl_xor(az, off);
            aw += __shfl_xor(aw, off);
        }
        if (g == 0) {
            float4 o;
            o.x = 1.f / (1.f + expf(-ax));
            o.y = 1.f / (1.f + expf(-ay));
            o.z = 1.f / (1.f + expf(-az));
            o.w = 1.f / (1.f + expf(-aw));
            *(float4*)(out_enc + (size_t)u * 4) = o;
        }
    }
}

// ===========================================================================
// FALLBACK (proven R6): single-block LDS sort + transpose + RS-based fused.
// ===========================================================================
#define SORT_SMEM (65536 + 65536 + 4096 + 64)

__global__ __launch_bounds__(1024) void sort_transpose_kernel(
    const int* __restrict__ vocab_ids,
    const float* __restrict__ W1,
    unsigned int* __restrict__ G,
    unsigned short* __restrict__ RS,
    unsigned short* __restrict__ WtG,
    float* __restrict__ out_ids) {
    const int t = threadIdx.x;
    if (blockIdx.x != 0) {
        int idx = (blockIdx.x - 1) * 1024 + t;
        if (idx < DMID * DIN) {
            int c = idx / DIN;
            int k = idx - c * DIN;
            WtG[idx] = (unsigned short)f2bf(W1[k * DMID + c]);
        }
        return;
    }
    extern __shared__ char smem[];
    unsigned* Gs     = (unsigned*)smem;
    unsigned* histDM = (unsigned*)(smem + 65536);
    unsigned* sums   = (unsigned*)(smem + 131072);
    unsigned* totalU = (unsigned*)(smem + 135168);
    for (int e = t; e < NELEM; e += 1024)
        Gs[e] = ((unsigned)vocab_ids[e] << 14) | (unsigned)e;
    __syncthreads();
    for (int pass = 0; pass < 6; ++pass) {
        const int shift = 9 + pass * 4;
        unsigned v[16];
#pragma unroll
        for (int i = 0; i < 16; ++i) v[i] = Gs[t * 16 + i];
#pragma unroll
        for (int d = 0; d < 16; ++d) histDM[d * 1024 + t] = 0;
#pragma unroll
        for (int i = 0; i < 16; ++i) histDM[((v[i] >> shift) & 15u) * 1024 + t] += 1;
        __syncthreads();
        unsigned lex[16]; unsigned run = 0;
#pragma unroll
        for (int i = 0; i < 16; ++i) { unsigned x = histDM[t * 16 + i]; lex[i] = run; run += x; }
        sums[t] = run;
        __syncthreads();
        if (t < 64) {
            unsigned s[16]; unsigned tot = 0;
#pragma unroll
            for (int i = 0; i < 16; ++i) { unsigned x = sums[t * 16 + i]; s[i] = tot; tot += x; }
            unsigned incv = tot;
#pragma unroll
            for (int off = 1; off < 64; off <<= 1) {
                unsigned y = __shfl_up(incv, off);
                if (t >= off) incv += y;
            }
            unsigned excl = incv - tot;
#pragma unroll
            for (int i = 0; i < 16; ++i) sums[t * 16 + i] = excl + s[i];
        }
        __syncthreads();
#pragma unroll
        for (int i = 0; i < 16; ++i) histDM[t * 16 + i] = sums[t] + lex[i];
        __syncthreads();
        unsigned mycnt[16];
#pragma unroll
        for (int d = 0; d < 16; ++d) mycnt[d] = histDM[d * 1024 + t];
#pragma unroll
        for (int i = 0; i < 16; ++i) {
            unsigned d = (v[i] >> shift) & 15u;
            Gs[mycnt[d]++] = v[i];
        }
        __syncthreads();
    }
    unsigned v[16];
#pragma unroll
    for (int i = 0; i < 16; ++i) v[i] = Gs[t * 16 + i];
    unsigned pk = (t == 0) ? 0xFFFFFFFFu : (Gs[t * 16 - 1] >> 9);
    unsigned fm = 0;
#pragma unroll
    for (int i = 0; i < 16; ++i) {
        unsigned key = v[i] >> 9;
        if (key != pk) fm |= (1u << i);
        pk = key;
    }
    sums[t] = (unsigned)__popc(fm);
    __syncthreads();
    if (t < 64) {
        unsigned s[16]; unsigned tot = 0;
#pragma unroll
        for (int i = 0; i < 16; ++i) { unsigned x = sums[t * 16 + i]; s[i] = tot; tot += x; }
        unsigned incv = tot;
#pragma unroll
        for (int off = 1; off < 64; off <<= 1) {
            unsigned y = __shfl_up(incv, off);
            if (t >= off) incv += y;
        }
        unsigned excl = incv - tot;
#pragma unroll
        for (int i = 0; i < 16; ++i) sums[t * 16 + i] = excl + s[i];
        if (t == 63) *totalU = incv;
    }
    __syncthreads();
    unsigned r = sums[t];
#pragma unroll
    for (int i = 0; i < 16; ++i) {
        if (fm & (1u << i)) {
            RS[r] = (unsigned short)(t * 16 + i);
            out_ids[2 * r + 0] = (float)(v[i] >> 14);
            out_ids[2 * r + 1] = (float)((v[i] >> 9) & 31u);
            ++r;
        }
    }
    const unsigned U = *totalU;
    for (int u = t; u < NELEM; u += 1024) {
        if ((unsigned)u >= U) {
            RS[u] = (unsigned short)NELEM;
            out_ids[2 * u + 0] = 0.0f;
            out_ids[2 * u + 1] = 0.0f;
        }
        G[u] = Gs[u];
    }
    if (t == 0) RS[NELEM] = (unsigned short)NELEM;
}

__global__ __launch_bounds__(256) void fused_kernel_rs(
    const unsigned* __restrict__ G,
    const unsigned short* __restrict__ RS,
    const unsigned short* __restrict__ WtG,
    const float* __restrict__ emb,
    const float* __restrict__ b1,
    const float* __restrict__ enc,
    float* __restrict__ out_enc) {
    __shared__ char smem[20736];
    const int t = threadIdx.x;
    const int u0 = blockIdx.x * FBM;
    const int l = t & 63;
    const int w = t >> 6;
    const int ar = t >> 4;
    const int ak4 = t & 15;
    const int rs_a = (int)RS[u0 + ar];
    const int re_a = (int)RS[u0 + ar + 1];
    f32x4 acc0 = {0.f, 0.f, 0.f, 0.f};
    f32x4 acc1 = {0.f, 0.f, 0.f, 0.f};
    for (int kk = 0; kk < DIN; kk += 64) {
        __syncthreads();
        {
            float s0 = 0.f, s1 = 0.f, s2 = 0.f, s3 = 0.f;
            const float* base = emb + (size_t)(kk + ak4 * 4);
            for (int p = rs_a; p < re_a; ++p) {
                unsigned idx = G[p] & 16383u;
                const float4 e4 = *(const float4*)(base + (size_t)idx * DIN);
                s0 += e4.x; s1 += e4.y; s2 += e4.z; s3 += e4.w;
            }
            uint2 packed;
            packed.x = f2bf(s0) | (f2bf(s1) << 16);
            packed.y = f2bf(s2) | (f2bf(s3) << 16);
            *(uint2*)(smem + ar * 144 + ak4 * 8) = packed;
        }
        {
#pragma unroll
            for (int i = 0; i < 4; ++i) {
                int q = t + i * 256;
                int c = q >> 3;
                int uo = q & 7;
                uint4 dv = *(const uint4*)(WtG + (size_t)c * DIN + kk + uo * 8);
                *(uint4*)(smem + 2304 + c * 144 + uo * 16) = dv;
            }
        }
        __syncthreads();
        {
            const int arow = l & 15;
            const int ull = l >> 4;
#pragma unroll
            for (int kf = 0; kf < 2; ++kf) {
                short8 aF = *(const short8*)(smem + arow * 144 + kf * 64 + ull * 16);
                short8 bF0 = *(const short8*)(smem + 2304 + (w * 32 + arow) * 144 + kf * 64 + ull * 16);
                short8 bF1 = *(const short8*)(smem + 2304 + (w * 32 + 16 + arow) * 144 + kf * 64 + ull * 16);
                acc0 = __builtin_amdgcn_mfma_f32_16x16x32_bf16(aF, bF0, acc0, 0, 0, 0);
                acc1 = __builtin_amdgcn_mfma_f32_16x16x32_bf16(aF, bF1, acc1, 0, 0, 0);
            }
        }
    }
    __syncthreads();
    {
        float* Hs = (float*)smem;
        const int col0 = w * 32 + (l & 15);
        const int rbase = (l >> 4) * 4;
#pragma unroll
        for (int reg = 0; reg < 4; ++reg) {
            Hs[(rbase + reg) * 132 + col0] = tanhf(acc0[reg] + b1[col0]);
            Hs[(rbase + reg) * 132 + col0 + 16] = tanhf(acc1[reg] + b1[col0 + 16]);
        }
    }
    __syncthreads();
    {
        const float* Hs = (const float*)smem;
        const int r = t >> 4;
        const int g = t & 15;
        const int u = u0 + r;
        const int rs = (int)RS[u];
        const int re = (int)RS[u + 1];
        unsigned vocab = (rs < re) ? (G[rs] >> 14) : 0u;
        const float4* wrow = (const float4*)(enc + (size_t)vocab * (DMID * DOUT));
        float ax = 0.f, ay = 0.f, az = 0.f, aw = 0.f;
#pragma unroll
        for (int jj = 0; jj < 8; ++jj) {
            int j = jj * 16 + g;
            float4 w4 = wrow[j];
            float hv = Hs[r * 132 + j];
            ax += hv * w4.x; ay += hv * w4.y; az += hv * w4.z; aw += hv * w4.w;
        }
#pragma unroll
        for (int off = 1; off < 16; off <<= 1) {
            ax += __shfl_xor(ax, off);
            ay += __shfl_xor(ay, off);
            az += __shfl_xor(az, off);
            aw += __shfl_xor(aw, off);
        }
        if (g == 0) {
            float4 o;
            o.x = 1.f / (1.f + expf(-ax));
            o.y = 1.f / (1.f + expf(-ay));
            o.z = 1.f / (1.f + expf(-az));
            o.w = 1.f / (1.f + expf(-aw));
            *(float4*)(out_enc + (size_t)u * 4) = o;
        }
    }
}

// ---------------------------------------------------------------------------
extern "C" void kernel_launch(void* const* d_in, const int* in_sizes, int n_in,
                              void* d_out, int out_size, void* d_ws, size_t ws_size,
                              hipStream_t stream) {
    const int*   vocab_ids = (const int*)d_in[0];
    const float* emb       = (const float*)d_in[1];
    const float* W1        = (const float*)d_in[2];
    const float* b1        = (const float*)d_in[3];
    const float* enc       = (const float*)d_in[4];
    float* out = (float*)d_out;
    float* out_ids = out;
    float* out_enc = out + NELEM * 2;
    char* ws = (char*)d_ws;

    if (ws_size >= FAST4_WS) {
        unsigned*           Gb     = (unsigned*)(ws + 0);
        unsigned*           SD     = (unsigned*)(ws + 65536);
        unsigned short*     WtG    = (unsigned short*)(ws + 131072);
        unsigned long long* stage  = (unsigned long long*)(ws + 327680);
        unsigned*           LCnt   = (unsigned*)(ws + 458752);
        unsigned*           bitmap = (unsigned*)(ws + 458880);

        hipMemsetAsync(bitmap, 0, BMBYTES, stream);
        prep_kernel<<<32, 256, 0, stream>>>(vocab_ids, W1, Gb, WtG, bitmap, stage, LCnt);
        rank_kernel<<<32, 256, 0, stream>>>(bitmap, stage, LCnt, SD, out_ids);
        fused_kernel<<<NELEM / FBM, 256, 0, stream>>>(Gb, SD, WtG, emb, b1, enc, out_enc);
    } else {
        unsigned int*   G   = (unsigned int*)(ws);
        unsigned short* RS  = (unsigned short*)(ws + 65536);
        unsigned short* WtG = (unsigned short*)(ws + 98432);

        hipFuncSetAttribute((const void*)sort_transpose_kernel,
                            hipFuncAttributeMaxDynamicSharedMemorySize, SORT_SMEM);
        sort_transpose_kernel<<<1 + 96, 1024, SORT_SMEM, stream>>>(
            vocab_ids, W1, G, RS, WtG, out_ids);
        fused_kernel_rs<<<NELEM / FBM, 256, 0, stream>>>(G, RS, WtG, emb, b1, enc, out_enc);
    }
}